// Round 22
// baseline (199.099 us; speedup 1.0000x reference)
//
#include <hip/hip_runtime.h>
#include <hip/hip_bf16.h>
#include <cmath>

#define D_MODEL 128
#define NUM_HEAD 4
#define HEAD_DIM 32
#define SEQ 4096
#define BATCH 2
#define RROWS 8    // token rows per projection block

typedef __attribute__((ext_vector_type(8))) short short8;
typedef __attribute__((ext_vector_type(4))) float f32x4;

__device__ __forceinline__ float tof(float x) { return x; }
__device__ __forceinline__ float tof(__hip_bfloat16 x) { return __bfloat162float(x); }
__device__ __forceinline__ void storef(float* p, size_t i, float v) { p[i] = v; }
__device__ __forceinline__ void storef(__hip_bfloat16* p, size_t i, float v) { p[i] = __float2bfloat16(v); }

// manual RNE split: x = hi + lo in bf16, error ~2^-18 relative
__device__ __forceinline__ void split_bf16(float x, unsigned short& hi, unsigned short& lo)
{
    const unsigned u = __float_as_uint(x);
    const unsigned r = u + 0x7FFFu + ((u >> 16) & 1u);
    hi = (unsigned short)(r >> 16);
    const float hf = __uint_as_float((unsigned)hi << 16);
    const float lf = x - hf;
    const unsigned ul = __float_as_uint(lf);
    const unsigned rl = ul + 0x7FFFu + ((ul >> 16) & 1u);
    lo = (unsigned short)(rl >> 16);
}
// hi-only RNE round (for P, whose lo term is dropped in PV)
__device__ __forceinline__ unsigned short rne_bf16(float x)
{
    const unsigned u = __float_as_uint(x);
    return (unsigned short)((u + 0x7FFFu + ((u >> 16) & 1u)) >> 16);
}

// ---------------------------------------------------------------------------
// Kernel 0: dtype detector (f32 vs bf16 inputs), unchanged (passes since R3).
// ---------------------------------------------------------------------------
__global__ void detect_kernel(const unsigned short* __restrict__ w, int* __restrict__ flag)
{
    const int t = threadIdx.x;   // 64 threads
    int weird = 0;
#pragma unroll
    for (int j = 0; j < 4; ++j) {
        const unsigned short v = w[(t * 4 + j) * 2 + 1];
        const float x = __uint_as_float((unsigned)v << 16);
        const float a = fabsf(x);
        if (a > 1e20f || (a > 0.f && a < 1e-20f)) weird++;
    }
#pragma unroll
    for (int off = 32; off; off >>= 1) weird += __shfl_xor(weird, off);
    if (t == 0) *flag = (weird < 32) ? 1 : 0;
}

// ---------------------------------------------------------------------------
// Kernel 0b (R22): ONE prep kernel = weight transpose (4 mats -> f32 Wt[d][e],
// R21-verified -27us) + PE table pe[s][e] (f64 transcendentals computed ONCE
// here instead of in every qkv wave — R21's diagnosed qkv latency tax).
// grid (36, 64) x 256: x<4 -> weights, x>=4 -> pe rows.
// ---------------------------------------------------------------------------
__global__ __launch_bounds__(256) void prep_kernel(
    const void* w0, const void* w1, const void* w2, const void* w3,
    float* __restrict__ wt, float* __restrict__ peTab,
    const int* __restrict__ flag)
{
    const int bx = blockIdx.x;
    if (bx < 4) {
        const int idx = blockIdx.y * 256 + threadIdx.x;   // 0..16383
        const void* w = (bx == 0) ? w0 : (bx == 1) ? w1 : (bx == 2) ? w2 : w3;
        const int e = idx >> 7, d = idx & 127;
        const float v = (*flag) ? ((const float*)w)[idx]
                                : tof(((const __hip_bfloat16*)w)[idx]);
        wt[(size_t)bx * 16384 + (size_t)d * 128 + e] = v;
    } else {
        const int idx = ((bx - 4) * 64 + blockIdx.y) * 256 + threadIdx.x;  // 0..524287
        const int s = idx >> 7, e = idx & 127;
        const int i = e >> 1;
        const double ang = (double)s / pow(10000.0, (double)i / 64.0);
        peTab[idx] = (float)((e & 1) ? cos(ang) : sin(ang));
    }
}

// ---------------------------------------------------------------------------
// Kernel 1: x = embedding[seq] + peTab;  Q/K/V = x @ Wt, emitted as SPLIT
// bf16. R22: PE from table (no f64 in the hot path).
// ---------------------------------------------------------------------------
template <typename T>
__device__ __forceinline__ void qkv_body(
    const int* __restrict__ seq, const T* __restrict__ emb,
    const float* __restrict__ wqt, const float* __restrict__ wkt,
    const float* __restrict__ wvt, const float* __restrict__ peTab,
    unsigned short* __restrict__ Qhi, unsigned short* __restrict__ Qlo,
    unsigned short* __restrict__ Khi, unsigned short* __restrict__ Klo,
    unsigned short* __restrict__ Vthi, unsigned short* __restrict__ Vtlo)
{
    const int e = threadIdx.x;               // 0..127 output dim
    const int r0 = blockIdx.x * RROWS;
    __shared__ __align__(16) float xs[RROWS][D_MODEL];
    __shared__ __align__(16) unsigned short vsh[2][RROWS][D_MODEL];

#pragma unroll
    for (int r = 0; r < RROWS; ++r) {
        const int s = (r0 + r) & (SEQ - 1);
        xs[r][e] = tof(emb[(size_t)seq[r0 + r] * D_MODEL + e]) + peTab[(size_t)s * D_MODEL + e];
    }
    __syncthreads();

    float aq[RROWS], ak[RROWS], av[RROWS];
#pragma unroll
    for (int r = 0; r < RROWS; ++r) { aq[r] = 0.f; ak[r] = 0.f; av[r] = 0.f; }

    for (int d = 0; d < D_MODEL; d += 4) {
        float4 xr[RROWS];
#pragma unroll
        for (int r = 0; r < RROWS; ++r) xr[r] = *(const float4*)&xs[r][d];
#pragma unroll
        for (int dd = 0; dd < 4; ++dd) {
            const float wq_ = wqt[(size_t)(d + dd) * 128 + e];   // coalesced
            const float wk_ = wkt[(size_t)(d + dd) * 128 + e];
            const float wv_ = wvt[(size_t)(d + dd) * 128 + e];
#pragma unroll
            for (int r = 0; r < RROWS; ++r) {
                const float x = (dd == 0) ? xr[r].x : (dd == 1) ? xr[r].y
                              : (dd == 2) ? xr[r].z : xr[r].w;
                aq[r] += x * wq_; ak[r] += x * wk_; av[r] += x * wv_;
            }
        }
    }
    const float scale = 0.17677669529663687f;   // 1/sqrt(32) folded into Q
#pragma unroll
    for (int r = 0; r < RROWS; ++r) {
        const size_t o = (size_t)(r0 + r) * D_MODEL + e;
        unsigned short hi, lo;
        split_bf16(aq[r] * scale, hi, lo); Qhi[o] = hi; Qlo[o] = lo;
        split_bf16(ak[r], hi, lo);         Khi[o] = hi; Klo[o] = lo;
        split_bf16(av[r], hi, lo);         vsh[0][r][e] = hi; vsh[1][r][e] = lo;
    }
    __syncthreads();

    // coalesced V^T store: head-row k = (s&1023)*4 + e/32, head-dim = e&31
    {
        const int b  = r0 >> 12;
        const int s0 = r0 & (SEQ - 1);
        const int h  = s0 >> 10;
        const size_t vtb = (size_t)(b * 4 + h) * (32 * SEQ);
        const int d = e >> 2;                // 0..31 head-dim
        const int j = e & 3;                 // 8-k segment
        const int kk0 = (s0 & 1023) << 2;
#pragma unroll
        for (int hl = 0; hl < 2; ++hl) {
            short8 tmp;
#pragma unroll
            for (int i = 0; i < 8; ++i) {
                const int kl = j * 8 + i;
                tmp[i] = (short)vsh[hl][kl >> 2][(kl & 3) * 32 + d];
            }
            unsigned short* dst = (hl ? Vtlo : Vthi) + vtb + (size_t)d * SEQ + kk0 + j * 8;
            *(short8*)dst = tmp;
        }
    }
}

__global__ __launch_bounds__(128) void qkv_kernel(
    const int* __restrict__ seq, const void* emb,
    const float* __restrict__ wqt, const float* __restrict__ wkt,
    const float* __restrict__ wvt, const float* __restrict__ peTab,
    unsigned short* Qhi, unsigned short* Qlo,
    unsigned short* Khi, unsigned short* Klo,
    unsigned short* Vthi, unsigned short* Vtlo,
    const int* __restrict__ flag)
{
    if (*flag)
        qkv_body<float>(seq, (const float*)emb, wqt, wkt, wvt, peTab,
                        Qhi, Qlo, Khi, Klo, Vthi, Vtlo);
    else
        qkv_body<__hip_bfloat16>(seq, (const __hip_bfloat16*)emb, wqt, wkt, wvt, peTab,
                                 Qhi, Qlo, Khi, Klo, Vthi, Vtlo);
}

// ---------------------------------------------------------------------------
// Kernel 2: MFMA flash attention — UNCHANGED from R20/R21 (verified ~105us,
// absmax 0.0156). 1024-thr block = 16 waves = 4 waves/SIMD; 48 VGPR fits
// the 64-cap; wave = (rt, kh-quarter); 6 QK + 4 PV MFMAs per 32-col chunk;
// pbuf/comb LDS union; exact 4-way kh combine.
// ---------------------------------------------------------------------------
__global__ __launch_bounds__(1024, 1) void attn_kernel(
    const unsigned short* __restrict__ Qhi, const unsigned short* __restrict__ Qlo,
    const unsigned short* __restrict__ Khi, const unsigned short* __restrict__ Klo,
    const unsigned short* __restrict__ Vthi, const unsigned short* __restrict__ Vtlo,
    float* __restrict__ A)
{
    const int bh   = blockIdx.x;
    const int pair = blockIdx.y;
    const size_t baseQ  = (size_t)(bh >> 2) * SEQ * D_MODEL + (size_t)(bh & 3) * SEQ * HEAD_DIM;
    const size_t baseVt = (size_t)bh * (32 * SEQ);

    const int tid  = threadIdx.x;
    const int wid  = __builtin_amdgcn_readfirstlane(tid >> 6);
    const int lane = tid & 63;
    const int rt   = wid & 3;
    const int kh   = wid >> 2;
    const int quad = lane >> 4;
    const int col  = lane & 15;

    __shared__ float shbuf[16 * 560];
    float* pb = &shbuf[wid * 560];

#pragma unroll
    for (int ti = 0; ti < 2; ++ti) {
        const int qt = ti ? pair : (63 - pair);
        const int qrow0 = qt * 64 + rt * 16;

        short8 qhiF, qloF;
        {
            const size_t qo = baseQ + (size_t)(qrow0 + col) * HEAD_DIM + quad * 8;
            qhiF = *(const short8*)(Qhi + qo);
            qloF = *(const short8*)(Qlo + qo);
        }

        f32x4 O0 = {0.f, 0.f, 0.f, 0.f};
        f32x4 O1 = {0.f, 0.f, 0.f, 0.f};
        float m[4] = {0.f, 0.f, 0.f, 0.f};
        float l[4] = {0.f, 0.f, 0.f, 0.f};

        const int N   = 2 * (qt + 1);
        const int nb  = N >> 2, rem = N & 3;
        const int cnt  = nb + ((kh < rem) ? 1 : 0);
        const int cbeg = kh * nb + ((kh < rem) ? kh : rem);

        for (int c = cbeg; c < cbeg + cnt; ++c) {
            const int kbase = c * 32;
            const size_t k0o = baseQ + (size_t)(kbase + col) * HEAD_DIM + quad * 8;
            const size_t k1o = baseQ + (size_t)(kbase + 16 + col) * HEAD_DIM + quad * 8;
            const short8 k0h = *(const short8*)(Khi + k0o);
            const short8 k0l = *(const short8*)(Klo + k0o);
            const short8 k1h = *(const short8*)(Khi + k1o);
            const short8 k1l = *(const short8*)(Klo + k1o);

            f32x4 s0 = {0.f, 0.f, 0.f, 0.f};
            f32x4 s1 = {0.f, 0.f, 0.f, 0.f};
            s0 = __builtin_amdgcn_mfma_f32_16x16x32_bf16(qhiF, k0h, s0, 0, 0, 0);
            s0 = __builtin_amdgcn_mfma_f32_16x16x32_bf16(qhiF, k0l, s0, 0, 0, 0);
            s0 = __builtin_amdgcn_mfma_f32_16x16x32_bf16(qloF, k0h, s0, 0, 0, 0);
            s1 = __builtin_amdgcn_mfma_f32_16x16x32_bf16(qhiF, k1h, s1, 0, 0, 0);
            s1 = __builtin_amdgcn_mfma_f32_16x16x32_bf16(qhiF, k1l, s1, 0, 0, 0);
            s1 = __builtin_amdgcn_mfma_f32_16x16x32_bf16(qloF, k1h, s1, 0, 0, 0);

            float p0[4], p1[4], cm[4];
#pragma unroll
            for (int r = 0; r < 4; ++r) {
                const int rowg = qrow0 + quad * 4 + r;
                p0[r] = (kbase + col      <= rowg) ? fabsf(s0[r]) : -1.f;
                p1[r] = (kbase + 16 + col <= rowg) ? fabsf(s1[r]) : -1.f;
                cm[r] = fmaxf(p0[r], p1[r]);
            }
#pragma unroll
            for (int off = 1; off < 16; off <<= 1) {
#pragma unroll
                for (int r = 0; r < 4; ++r) cm[r] = fmaxf(cm[r], __shfl_xor(cm[r], off, 64));
            }
#pragma unroll
            for (int r = 0; r < 4; ++r) {
                const float nm = fmaxf(m[r], cm[r]);
                const float al = __expf(m[r] - nm);
                l[r] *= al; O0[r] *= al; O1[r] *= al; m[r] = nm;
            }
#pragma unroll
            for (int r = 0; r < 4; ++r) {
                const float e0 = (p0[r] >= 0.f) ? __expf(p0[r] - m[r]) : 0.f;
                const float e1 = (p1[r] >= 0.f) ? __expf(p1[r] - m[r]) : 0.f;
                l[r] += e0 + e1;
                pb[(quad * 4 + r) * 34 + col]      = e0;
                pb[(quad * 4 + r) * 34 + 16 + col] = e1;
            }
            short8 ph;
            {
                const float* pr = &pb[col * 34 + quad * 8];
#pragma unroll
                for (int j = 0; j < 8; ++j) ph[j] = (short)rne_bf16(pr[j]);
            }
            const size_t v0o = baseVt + (size_t)col * SEQ + kbase + quad * 8;
            const size_t v1o = baseVt + (size_t)(16 + col) * SEQ + kbase + quad * 8;
            const short8 v0h = *(const short8*)(Vthi + v0o);
            const short8 v0l = *(const short8*)(Vtlo + v0o);
            const short8 v1h = *(const short8*)(Vthi + v1o);
            const short8 v1l = *(const short8*)(Vtlo + v1o);

            O0 = __builtin_amdgcn_mfma_f32_16x16x32_bf16(ph, v0h, O0, 0, 0, 0);
            O0 = __builtin_amdgcn_mfma_f32_16x16x32_bf16(ph, v0l, O0, 0, 0, 0);
            O1 = __builtin_amdgcn_mfma_f32_16x16x32_bf16(ph, v1h, O1, 0, 0, 0);
            O1 = __builtin_amdgcn_mfma_f32_16x16x32_bf16(ph, v1l, O1, 0, 0, 0);
        }

#pragma unroll
        for (int off = 1; off < 16; off <<= 1) {
#pragma unroll
            for (int r = 0; r < 4; ++r) l[r] += __shfl_xor(l[r], off, 64);
        }

        __syncthreads();
        {
            float* cb = &shbuf[(rt * 4 + kh) * 560];
#pragma unroll
            for (int r = 0; r < 4; ++r) {
                const int row = quad * 4 + r;
                cb[row * 35 + col]      = O0[r];
                cb[row * 35 + 16 + col] = O1[r];
            }
            if (col == 0) {
#pragma unroll
                for (int r = 0; r < 4; ++r) {
                    cb[(quad * 4 + r) * 35 + 32] = m[r];
                    cb[(quad * 4 + r) * 35 + 33] = l[r];
                }
            }
        }
        __syncthreads();
        if (kh == 0) {
            const int row = lane >> 2;
            const int d8  = (lane & 3) * 8;
            float M = 0.f;
#pragma unroll
            for (int q = 0; q < 4; ++q)
                M = fmaxf(M, shbuf[(rt * 4 + q) * 560 + row * 35 + 32]);
            float a[4], L = 0.f;
#pragma unroll
            for (int q = 0; q < 4; ++q) {
                a[q] = __expf(shbuf[(rt * 4 + q) * 560 + row * 35 + 32] - M);
                L += a[q] * shbuf[(rt * 4 + q) * 560 + row * 35 + 33];
            }
            const float invL = 1.f / L;
            float* Ao = A + baseQ + (size_t)(qrow0 + row) * HEAD_DIM + d8;
#pragma unroll
            for (int d = 0; d < 8; ++d) {
                float o = 0.f;
#pragma unroll
                for (int q = 0; q < 4; ++q)
                    o += a[q] * shbuf[(rt * 4 + q) * 560 + row * 35 + d8 + d];
                Ao[d] = o * invL;
            }
        }
        __syncthreads();
    }
}

// ---------------------------------------------------------------------------
// Kernel 3: out = att @ Wo^T  (coalesced pre-transposed wo reads)
// ---------------------------------------------------------------------------
template <typename T>
__device__ __forceinline__ void out_proj_body(
    const float* __restrict__ att, const float* __restrict__ wot, T* __restrict__ out)
{
    const int e = threadIdx.x;
    const int r0 = blockIdx.x * RROWS;
    __shared__ __align__(16) float xs[RROWS][D_MODEL];
#pragma unroll
    for (int r = 0; r < RROWS; ++r)
        xs[r][e] = att[(size_t)(r0 + r) * D_MODEL + e];
    __syncthreads();

    float acc[RROWS];
#pragma unroll
    for (int r = 0; r < RROWS; ++r) acc[r] = 0.f;
    for (int d = 0; d < D_MODEL; d += 4) {
        float4 xr[RROWS];
#pragma unroll
        for (int r = 0; r < RROWS; ++r) xr[r] = *(const float4*)&xs[r][d];
#pragma unroll
        for (int dd = 0; dd < 4; ++dd) {
            const float w_ = wot[(size_t)(d + dd) * 128 + e];   // coalesced
#pragma unroll
            for (int r = 0; r < RROWS; ++r) {
                const float x = (dd == 0) ? xr[r].x : (dd == 1) ? xr[r].y
                              : (dd == 2) ? xr[r].z : xr[r].w;
                acc[r] += x * w_;
            }
        }
    }
#pragma unroll
    for (int r = 0; r < RROWS; ++r)
        storef(out, (size_t)(r0 + r) * D_MODEL + e, acc[r]);
}

__global__ __launch_bounds__(128) void out_proj_kernel(
    const float* __restrict__ att, const float* __restrict__ wot, void* out,
    const int* __restrict__ flag)
{
    if (*flag)
        out_proj_body<float>(att, wot, (float*)out);
    else
        out_proj_body<__hip_bfloat16>(att, wot, (__hip_bfloat16*)out);
}

extern "C" void kernel_launch(void* const* d_in, const int* in_sizes, int n_in,
                              void* d_out, int out_size, void* d_ws, size_t ws_size,
                              hipStream_t stream) {
    const int* seq = (const int*)d_in[0];
    const void* emb = d_in[1];
    const void* wq  = d_in[2];
    const void* wk  = d_in[3];
    const void* wv  = d_in[4];
    const void* wo  = d_in[5];

    const size_t N = (size_t)BATCH * SEQ * D_MODEL;   // 1,048,576 elements
    int*            flag = (int*)d_ws;
    unsigned short* Qhi  = (unsigned short*)((char*)d_ws + 256);
    unsigned short* Qlo  = Qhi + N;
    unsigned short* Khi  = Qlo + N;
    unsigned short* Klo  = Khi + N;
    unsigned short* Vthi = Klo + N;
    unsigned short* Vtlo = Vthi + N;
    float*          A    = (float*)(Vtlo + N);        // fp32 attn output (4 MB)
    float*          wt   = A + N;                     // 4 x 128x128 f32 transposed
    float*          pe   = wt + 4 * 16384;            // PE table 4096x128 f32 (2 MB)

    detect_kernel<<<dim3(1), dim3(64), 0, stream>>>((const unsigned short*)wq, flag);
    prep_kernel<<<dim3(36, 64), dim3(256), 0, stream>>>(wq, wk, wv, wo, wt, pe, flag);
    qkv_kernel<<<dim3(BATCH * SEQ / RROWS), dim3(128), 0, stream>>>(
        seq, emb, wt, wt + 16384, wt + 32768, pe,
        Qhi, Qlo, Khi, Klo, Vthi, Vtlo, flag);
    attn_kernel<<<dim3(BATCH * NUM_HEAD, 32), dim3(1024), 0, stream>>>(
        Qhi, Qlo, Khi, Klo, Vthi, Vtlo, A);
    out_proj_kernel<<<dim3(BATCH * SEQ / RROWS), dim3(128), 0, stream>>>(
        A, wt + 49152, d_out, flag);
}